// Round 5
// baseline (312.474 us; speedup 1.0000x reference)
//
#include <hip/hip_runtime.h>
#include <hip/hip_bf16.h>
#include <math.h>

// Problem constants
#define TT   4096     // T
#define BB   16       // B
#define NTOK 65536    // B*T
#define CIN  512      // IN_FEATS
#define EF   256      // EMBED_FEATS
#define NE   1024     // NUM_EMBED

typedef __attribute__((ext_vector_type(8))) short bf16x8;
typedef __attribute__((ext_vector_type(4))) float f32x4;

static __device__ __forceinline__ unsigned short f2bf(float f) {
  unsigned int u = __float_as_uint(f);
  u += 0x7fffu + ((u >> 16) & 1u);          // RNE
  return (unsigned short)(u >> 16);
}

// async global->LDS, 16B per lane; LDS dest is wave-uniform base + lane*16
#define GLL(gsrc, ldst) \
  __builtin_amdgcn_global_load_lds((const __attribute__((address_space(1))) void*)(gsrc), \
                                   (__attribute__((address_space(3))) void*)(ldst), 16, 0, 0)

// ---------------------------------------------------------------------------
// K0: convert proj_w -> bf16; embed -> bf16*(-2); e_norm[k] = ||embed_k||^2;
// block 1792 zeroes hist/sse/cnt (replaces hipMemsetAsync).
// ---------------------------------------------------------------------------
__global__ __launch_bounds__(256) void k_prep(const float* __restrict__ Wf,
                                              const float* __restrict__ Ef,
                                              unsigned short* __restrict__ Wbf,
                                              unsigned short* __restrict__ Ebf,
                                              float* __restrict__ e_norm,
                                              unsigned int* __restrict__ hist,
                                              float* __restrict__ sse,
                                              unsigned int* __restrict__ cnt) {
  int bid = blockIdx.x;
  if (bid < 512) {                      // W: 256*512 = 131072 elems
    int i = bid * 256 + threadIdx.x;
    Wbf[i] = f2bf(Wf[i]);
  } else if (bid < 1536) {              // E scaled by -2 (exact): 262144 elems
    int i = (bid - 512) * 256 + threadIdx.x;
    Ebf[i] = f2bf(-2.0f * Ef[i]);
  } else if (bid < 1792) {              // e_norm: 256 blocks * 4 codes (1 wave/code)
    int w = threadIdx.x >> 6, l = threadIdx.x & 63;
    int k = (bid - 1536) * 4 + w;
    const float4 v4 = ((const float4*)(Ef + (size_t)k * EF))[l];
    float s = v4.x * v4.x + v4.y * v4.y + v4.z * v4.z + v4.w * v4.w;
    for (int off = 32; off; off >>= 1) s += __shfl_down(s, off);
    if (l == 0) e_norm[k] = s;
  } else {                              // zero hist[1024], sse, cnt
    int tid = threadIdx.x;
    *(uint4*)(hist + tid * 4) = (uint4){0u, 0u, 0u, 0u};
    if (tid == 0) { *sse = 0.f; *cnt = 0u; }
  }
}

// ---------------------------------------------------------------------------
// K1 (fused), 512 threads / 128 tokens per block, 512 blocks.
// launch_bounds arg=2 -> 128 VGPR cap.  LDS 80 KB -> 2 blocks/CU (2*80=160,
// exactly the pool; OccupancyPercent is the verification signal).
//
// R4 bug fixed here: abuf is 8192 SHORTS (16 KB, 128 rows x 64), so wbuf0
// starts at short 8192 (R4 had it at 4096 -> A rows 64..127 corrupted W
// rows 0..63 on even ks; absmax 5.5 -> 234).
//
//  phase1 (8 ks iters, fully unrolled): A-prefetch distance 2 ks (HBM
//    latency) via v0/v1 register buffers; W via GLL double-buffered LDS,
//    issued 1 ks ahead.  Counted beta barrier (vmcnt 36/20/0; queue at
//    beta(ks<6): [W(ks) 4][A(ks+1) 16][W(ks+1) 4][A(ks+2) 16] -> 36) +
//    alpha barrier (read-close).  sched_barrier(0) pins vmem issue order.
//  phase2: bias + x -> bf16 xs[128][256] swizzled; xsq += x^2.
//  phase3 (32 chunks x 32 codes): 4 rotating 16KB buffers, ONE barrier per
//    chunk: barrier(c) = {vmcnt(4|2|0) lgkmcnt(0); s_barrier} -- per-wave
//    lgkmcnt(0) closes chunk c-1 reads, so GLL(c+3) issued AFTER the
//    barrier may safely overwrite buffer (c-1)&3.  Pure-GLL vmem stream
//    (e_norm pre-copied to LDS entab).
//  phase4: argmin merge -> LDS fidx[128], hist, sse.
//  phase5: fused gather -> LDS transpose tile -> out[B][EF][TT]
//    (conflict-free read pass + nontemporal stores).
//  tail:   device-scope done-counter; 512th block finalizes entropy/loss
//    (replaces k_final; agent-scope atomic loads for hist/sse).
// ---------------------------------------------------------------------------
__global__ __launch_bounds__(512, 2) void k_fused(const float* __restrict__ in,
                                                  const unsigned short* __restrict__ Wbf,
                                                  const float* __restrict__ bias,
                                                  const unsigned short* __restrict__ Ebf,
                                                  const float* __restrict__ e_norm,
                                                  const float* __restrict__ embed,
                                                  unsigned int* __restrict__ hist,
                                                  float* __restrict__ sse,
                                                  unsigned int* __restrict__ cnt,
                                                  float* __restrict__ out) {
  __shared__ unsigned short lds[40960];   // 80 KB
  // phase1 (shorts): abuf [0..8191], wbuf0 [8192..24575], wbuf1 [24576..40959]
  unsigned short* abuf = lds;
  unsigned short* xs = lds;               // phase2/3  x [128 t][256 e] 64 KB

  int tid = threadIdx.x;
  int w = tid >> 6, l = tid & 63;
  int l15 = l & 15, quad = l >> 4;
  int tq = w & 1, eq = w >> 1;            // phase1 MFMA mapping
  int cg = w & 3, th = w >> 2;            // phase1 A-load mapping
  int tok0 = blockIdx.x * 128;
  const float* src = in + (size_t)(tok0 >> 12) * CIN * TT + (tok0 & 4095);

  // ------------------ phase 1: projection GEMM ------------------
  f32x4 acc[4][4];
#pragma unroll
  for (int a = 0; a < 4; ++a)
#pragma unroll
    for (int b = 0; b < 4; ++b) acc[a][b] = (f32x4){0.f, 0.f, 0.f, 0.f};

  float v0[16], v1[16];
  {
    const float* sA = src + (size_t)(cg * 16) * TT + th * 64 + l;
#pragma unroll
    for (int i = 0; i < 16; ++i) v0[i] = __builtin_nontemporal_load(&sA[(size_t)i * TT]);
    __builtin_amdgcn_sched_barrier(0);
    // GLL W(0) -> wbuf0
#pragma unroll
    for (int i = 0; i < 4; ++i) {
      int g = i * 512 + tid;
      int row = g >> 3, pc = g & 7, lc = pc ^ (row & 7);
      GLL(Wbf + (size_t)row * CIN + lc * 8, lds + 8192 + g * 8);
    }
    __builtin_amdgcn_sched_barrier(0);
    const float* sB = src + (size_t)(64 + cg * 16) * TT + th * 64 + l;
#pragma unroll
    for (int i = 0; i < 16; ++i) v1[i] = __builtin_nontemporal_load(&sB[(size_t)i * TT]);
    __builtin_amdgcn_sched_barrier(0);
  }
  int trow = th * 64 + l;
#pragma unroll
  for (int ks = 0; ks < 8; ++ks) {        // fully unrolled: static counts/aliases
    unsigned short* wb = lds + 8192 + (ks & 1) * 16384;
    const float* vc = (ks & 1) ? v1 : v0;
    // convert A(ks) -> abuf (single-buffered: prior reads closed by alpha(ks-1))
#pragma unroll
    for (int cc = 0; cc < 2; ++cc) {
      alignas(16) unsigned short tmp[8];
#pragma unroll
      for (int j = 0; j < 8; ++j) tmp[j] = f2bf(vc[cc * 8 + j]);
      int c8 = cg * 2 + cc;
      int pc2 = c8 ^ (trow & 7);
      *(bf16x8*)(abuf + trow * 64 + pc2 * 8) = *(const bf16x8*)tmp;
    }
    if (ks < 7) {                         // GLL W(ks+1) -> other wbuf (dist 1)
#pragma unroll
      for (int i = 0; i < 4; ++i) {
        int g = i * 512 + tid;
        int row = g >> 3, pc = g & 7, lc = pc ^ (row & 7);
        GLL(Wbf + (size_t)row * CIN + (ks + 1) * 64 + lc * 8,
            lds + 8192 + ((ks + 1) & 1) * 16384 + g * 8);
      }
    }
    __builtin_amdgcn_sched_barrier(0);
    if (ks < 6) {                         // load A(ks+2) (dist 2, HBM latency)
      float* vn = (ks & 1) ? v1 : v0;
      const float* sN = src + (size_t)((ks + 2) * 64 + cg * 16) * TT + th * 64 + l;
#pragma unroll
      for (int i = 0; i < 16; ++i) vn[i] = __builtin_nontemporal_load(&sN[(size_t)i * TT]);
    }
    __builtin_amdgcn_sched_barrier(0);
    // beta barrier: W(ks) landed (counted), A ds_writes drained
    if (ks < 6)       asm volatile("s_waitcnt vmcnt(36) lgkmcnt(0)\n\ts_barrier" ::: "memory");
    else if (ks == 6) asm volatile("s_waitcnt vmcnt(20) lgkmcnt(0)\n\ts_barrier" ::: "memory");
    else              asm volatile("s_waitcnt vmcnt(0) lgkmcnt(0)\n\ts_barrier" ::: "memory");
#pragma unroll
    for (int kstep = 0; kstep < 2; ++kstep) {
      int ck = kstep * 4 + quad;
      bf16x8 af4[4], bfr[4];
#pragma unroll
      for (int msub = 0; msub < 4; ++msub) {
        int row = tq * 64 + msub * 16 + l15;
        int pa = ck ^ (row & 7);
        af4[msub] = *(const bf16x8*)(abuf + row * 64 + pa * 8);
      }
#pragma unroll
      for (int nsub = 0; nsub < 4; ++nsub) {
        int row = eq * 64 + nsub * 16 + l15;
        int pb = ck ^ (row & 7);
        bfr[nsub] = *(const bf16x8*)(wb + row * 64 + pb * 8);
      }
      __builtin_amdgcn_s_setprio(1);
#pragma unroll
      for (int msub = 0; msub < 4; ++msub)
#pragma unroll
        for (int nsub = 0; nsub < 4; ++nsub)
          acc[msub][nsub] = __builtin_amdgcn_mfma_f32_16x16x32_bf16(af4[msub], bfr[nsub],
                                                                    acc[msub][nsub], 0, 0, 0);
      __builtin_amdgcn_s_setprio(0);
    }
    // alpha barrier: this ks's LDS reads closed -> next ks may overwrite
    asm volatile("s_waitcnt lgkmcnt(0)\n\ts_barrier" ::: "memory");
  }

  // ------------------ phase 2: bias + x -> LDS xs, xsq ------------------
  float xsq = 0.f;
#pragma unroll
  for (int nsub = 0; nsub < 4; ++nsub) {
    int e = eq * 64 + nsub * 16 + l15;
    float bv = bias[e];
    int cx = e >> 3;
#pragma unroll
    for (int msub = 0; msub < 4; ++msub)
#pragma unroll
      for (int reg = 0; reg < 4; ++reg) {
        int m = tq * 64 + msub * 16 + quad * 4 + reg;
        float x = acc[msub][nsub][reg] + bv;
        xsq += x * x;
        int pcx = cx ^ (m & 31);
        xs[m * 256 + pcx * 8 + (e & 7)] = f2bf(x);
      }
  }
  __syncthreads();

  // ------------------ phase 3: A-frags to regs, 32x32-code chunk stream ----
  int g3 = w & 3, h = w >> 2;             // 32-token strip x 16-code half
  bf16x8 af[2][8];
#pragma unroll
  for (int msub = 0; msub < 2; ++msub)
#pragma unroll
    for (int kst = 0; kst < 8; ++kst) {
      int row = g3 * 32 + msub * 16 + l15;
      int c32 = kst * 4 + quad;
      int pcx = c32 ^ (row & 31);
      af[msub][kst] = *(const bf16x8*)(xs + row * 256 + pcx * 8);
    }
  __syncthreads();   // xs dead; LDS -> 4 x 16KB code buffers + entab

  // entab: full e_norm (1024 f32, 4 KB) at shorts 32768 (bytes 65536..69631)
  float* entab = (float*)(lds + 32768);
  {
    float2 ev = *(const float2*)(e_norm + (tid << 1));
    *(float2*)(entab + (tid << 1)) = ev;   // compiler drains the load first
  }
  __builtin_amdgcn_sched_barrier(0);
  // prologue: stage chunks 0,1,2 (PURE-GLL vmem stream from here on)
#pragma unroll
  for (int c = 0; c < 3; ++c)
#pragma unroll
    for (int i = 0; i < 2; ++i) {
      int g = i * 512 + tid;
      int row = g >> 5, pcc = g & 31, lc = pcc ^ row;
      GLL(Ebf + (size_t)(c * 32 + row) * EF + lc * 8, lds + c * 8192 + g * 8);
    }
  __builtin_amdgcn_sched_barrier(0);

  float best_v[2][4];
  int best_i[2][4];
#pragma unroll
  for (int a = 0; a < 2; ++a)
#pragma unroll
    for (int b = 0; b < 4; ++b) { best_v[a][b] = 3.0e38f; best_i[a][b] = 0; }

  int r3 = h * 16 + l15;                  // code row within chunk (0..31)
#pragma unroll 1
  for (int chunk = 0; chunk < 32; ++chunk) {
    unsigned short* eb = lds + (chunk & 3) * 8192;
    int c0 = chunk * 32;
    // ONE barrier per chunk: waits own GLL(chunk) (counted) + closes own
    // chunk-1 LDS reads (lgkm) -> after it, buffer (chunk-1)&3 is reusable.
    // queue entering: c<30: {c,c+1,c+2}=6 -> vmcnt(4); c==30: 4 -> vmcnt(2);
    // c==31: 2 -> vmcnt(0).
    if (chunk < 30)       asm volatile("s_waitcnt vmcnt(4) lgkmcnt(0)\n\ts_barrier" ::: "memory");
    else if (chunk == 30) asm volatile("s_waitcnt vmcnt(2) lgkmcnt(0)\n\ts_barrier" ::: "memory");
    else                  asm volatile("s_waitcnt vmcnt(0) lgkmcnt(0)\n\ts_barrier" ::: "memory");
    if (chunk <= 28) {                    // GLL(chunk+3) -> buffer (chunk-1)&3
      unsigned short* ebn = lds + ((chunk + 3) & 3) * 8192;
#pragma unroll
      for (int i = 0; i < 2; ++i) {
        int g = i * 512 + tid;
        int row = g >> 5, pcc = g & 31, lc = pcc ^ row;
        GLL(Ebf + (size_t)(c0 + 96 + row) * EF + lc * 8, ebn + g * 8);
      }
    }
    __builtin_amdgcn_sched_barrier(0);
    float en = entab[c0 + r3];            // LDS read, outside the vm stream
    f32x4 dacc[2];
    dacc[0] = (f32x4){en, en, en, en};
    dacc[1] = dacc[0];
    __builtin_amdgcn_s_setprio(1);
#pragma unroll
    for (int kst = 0; kst < 8; ++kst) {
      int cc = kst * 4 + quad;
      int pc = cc ^ r3;
      bf16x8 bfr = *(const bf16x8*)(eb + r3 * 256 + pc * 8);
      dacc[0] = __builtin_amdgcn_mfma_f32_16x16x32_bf16(af[0][kst], bfr, dacc[0], 0, 0, 0);
      dacc[1] = __builtin_amdgcn_mfma_f32_16x16x32_bf16(af[1][kst], bfr, dacc[1], 0, 0, 0);
    }
    __builtin_amdgcn_s_setprio(0);
    int code = c0 + r3;
#pragma unroll
    for (int msub = 0; msub < 2; ++msub)
#pragma unroll
      for (int reg = 0; reg < 4; ++reg) {
        float vv = dacc[msub][reg];
        if (vv < best_v[msub][reg]) { best_v[msub][reg] = vv; best_i[msub][reg] = code; }
      }
  }

  // ------------------ phase 4: argmin merge, outputs ------------------
#pragma unroll
  for (int msub = 0; msub < 2; ++msub)
#pragma unroll
    for (int reg = 0; reg < 4; ++reg) {
      float vv = best_v[msub][reg];
      int idx = best_i[msub][reg];
#pragma unroll
      for (int off = 8; off; off >>= 1) {
        float ov = __shfl_xor(vv, off, 16);
        int oi = __shfl_xor(idx, off, 16);
        if (ov < vv || (ov == vv && oi < idx)) { vv = ov; idx = oi; }
      }
      best_v[msub][reg] = vv;
      best_i[msub][reg] = idx;
    }
  float* red_v = (float*)lds;            // [2][128]  bytes 0..1023
  int* red_i = (int*)lds + 256;          // [2][128]  bytes 1024..2047
  float* xred = (float*)lds + 512;       // [8]       bytes 2048..2079
  float* svred = (float*)lds + 520;      // [2]       bytes 2080..2087
  int* fidx_w = (int*)lds + 544;         // [128]     bytes 2176..2687
  // NOTE: all phase-3 LDS reads were closed by the chunk-31 barrier's
  // lgkmcnt(0) per wave... but chunk 31 has no trailing barrier now, so the
  // __syncthreads() below is the first block-wide sync; red_v writes must
  // not race other waves' chunk-31 eb reads (buffer 3, bytes 24576+) --
  // red_v/red_i/xred/svred/fidx all < byte 2688, inside buffer 0, whose
  // last reads were chunk 28, closed by barrier(29..31).  Safe.
  if (l15 == 0) {
#pragma unroll
    for (int msub = 0; msub < 2; ++msub)
#pragma unroll
      for (int reg = 0; reg < 4; ++reg) {
        int tokloc = g3 * 32 + msub * 16 + quad * 4 + reg;
        red_v[h * 128 + tokloc] = best_v[msub][reg];
        red_i[h * 128 + tokloc] = best_i[msub][reg];
      }
  }
  for (int off = 32; off; off >>= 1) xsq += __shfl_down(xsq, off);
  if (l == 0) xred[w] = xsq;
  __syncthreads();
  if (tid < 128) {
    float v0r = red_v[tid], v1r = red_v[128 + tid];
    int i0 = red_i[tid], i1 = red_i[128 + tid];
    float vv; int idx;
    if (v1r < v0r || (v1r == v0r && i1 < i0)) { vv = v1r; idx = i1; } else { vv = v0r; idx = i0; }
    fidx_w[tid] = idx;                   // stays in LDS for phase 5
    atomicAdd(&hist[idx], 1u);
    for (int off = 32; off; off >>= 1) vv += __shfl_down(vv, off);
    if ((tid & 63) == 0) svred[tid >> 6] = vv;
  }
  __syncthreads();
  if (tid == 0) {
    float tot = svred[0] + svred[1];
#pragma unroll
    for (int i = 0; i < 8; ++i) tot += xred[i];
    atomicAdd(sse, tot);
  }

  // ------------------ phase 5: fused gather + transposed store ----------
  // embed rows by final index -> out[B][EF][TT], fp32 exact.  zq tile at
  // byte 4096..37375 -- disjoint from red/fidx scalar region (<2688).
  // Read pass bank-conflict-free (t = (tid&31)+32j, bank step 1); stores
  // nontemporal scalar dwords (128B-coalesced per half-wave).
  const int* fidx = (const int*)lds + 544;
  float* zq = (float*)lds + 1024;        // [128][65] floats, 33.3 KB
  int bnum = tok0 >> 12, t0 = tok0 & 4095;
  float* outb = out + (((size_t)bnum * EF) << 12) + t0;
#pragma unroll 1
  for (int et = 0; et < 4; ++et) {
    int e0 = et * 64;
#pragma unroll
    for (int rr = 0; rr < 4; ++rr) {
      int tl = rr * 32 + (tid >> 4);
      const float4 g4 = *(const float4*)(embed + (size_t)fidx[tl] * EF + e0 + (tid & 15) * 4);
      float* zr = zq + tl * 65 + (tid & 15) * 4;
      zr[0] = g4.x; zr[1] = g4.y; zr[2] = g4.z; zr[3] = g4.w;
    }
    __syncthreads();
#pragma unroll
    for (int rr = 0; rr < 4; ++rr) {
      int e = rr * 16 + (tid >> 5);
      float* orow = outb + ((size_t)(e0 + e) << 12);
#pragma unroll
      for (int j = 0; j < 4; ++j) {
        int t = (tid & 31) + 32 * j;
        __builtin_nontemporal_store(zq[t * 65 + e], &orow[t]);
      }
    }
    if (et < 3) __syncthreads();
  }

  // ------------------ tail: fused finalize (replaces k_final) -----------
  __syncthreads();
  int* flag = (int*)lds + 672;           // byte 2688, untouched by phase 5
  if (tid == 0) {
    __threadfence();                     // my hist/sse atomics complete+visible
    unsigned int done = __hip_atomic_fetch_add(cnt, 1u, __ATOMIC_ACQ_REL,
                                               __HIP_MEMORY_SCOPE_AGENT);
    *flag = (done == 511u) ? 1 : 0;
  }
  __syncthreads();
  if (*flag) {                           // last block: all 512 phase-4s done
    float local = 0.f;
#pragma unroll
    for (int i = 0; i < 2; ++i) {
      unsigned int hv = __hip_atomic_load(&hist[tid + i * 512], __ATOMIC_RELAXED,
                                          __HIP_MEMORY_SCOPE_AGENT);
      float p = (float)hv * (1.0f / 65536.0f);
      local -= p * logf(p + 1e-10f);
    }
    for (int off = 32; off; off >>= 1) local += __shfl_down(local, off);
    float* ered = (float*)lds + 512;     // reuse xred region
    if (l == 0) ered[w] = local;
    __syncthreads();
    if (tid == 0) {
      float lp = 0.f;
#pragma unroll
      for (int i = 0; i < 8; ++i) lp += ered[i];
      float sv = __hip_atomic_load(sse, __ATOMIC_RELAXED, __HIP_MEMORY_SCOPE_AGENT);
      out[16777216] = 1.25f * sv / 16777216.0f;  // vq + 0.25*commitment
      out[16777233] = lp;
    }
    if (tid < 16) out[16777217 + tid] = 6.93147180559945f * 4096.0f;  // log(1024)*4096
  }
}

// ---------------------------------------------------------------------------
extern "C" void kernel_launch(void* const* d_in, const int* in_sizes, int n_in,
                              void* d_out, int out_size, void* d_ws, size_t ws_size,
                              hipStream_t stream) {
  const float* inputs = (const float*)d_in[0];
  const float* proj_w = (const float*)d_in[1];
  const float* proj_b = (const float*)d_in[2];
  const float* embed = (const float*)d_in[3];
  float* out = (float*)d_out;
  char* ws = (char*)d_ws;

  // workspace layout
  unsigned short* Wbf  = (unsigned short*)(ws);            //   262,144 B
  unsigned short* Ebf  = (unsigned short*)(ws + 262144);   //   524,288 B
  float* e_norm        = (float*)(ws + 786432);            //     4,096 B
  unsigned int* hist   = (unsigned int*)(ws + 1052672);    //     4,096 B
  float* sse           = (float*)(ws + 1056768);           //         4 B
  unsigned int* cnt    = (unsigned int*)(ws + 1056772);    //         4 B
  if (ws_size < 1056776) return;

  k_prep<<<1793, 256, 0, stream>>>(proj_w, embed, Wbf, Ebf, e_norm, hist, sse, cnt);
  k_fused<<<512, 512, 0, stream>>>(inputs, Wbf, proj_b, Ebf, e_norm, embed,
                                   hist, sse, cnt, out);
}